// Round 1
// baseline (1940.314 us; speedup 1.0000x reference)
//
#include <hip/hip_runtime.h>

#define D 128
#define LVLS 18

// ---------------- embed: X[i,:] = data_vecs[data[i],:] @ data_W + data_b ----
__global__ __launch_bounds__(256) void embed_kernel(
    const int* __restrict__ data,
    const float* __restrict__ vecs,
    const float* __restrict__ W,
    const float* __restrict__ b,
    float* __restrict__ X,
    int N, int ntiles)
{
    __shared__ float w_s[D * D];    // 64KB
    __shared__ float a_s[32 * D];   // 16KB
    const int t = threadIdx.x;

    // stage W once per block (row-major [k][d], same as LDS layout)
    for (int i = t; i < D * D / 4; i += 256)
        ((float4*)w_s)[i] = ((const float4*)W)[i];

    const int cg = t & 31;   // cols 4cg..4cg+3
    const int ng = t >> 5;   // nodes ng, ng+8, ng+16, ng+24 (relative)
    const float4 b4 = ((const float4*)b)[cg];

    for (int tile = blockIdx.x; tile < ntiles; tile += gridDim.x) {
        const int base = tile * 32;
        __syncthreads();   // protect a_s (previous tile still reading)
        {   // stage 32 gathered rows: 4096 floats = 1024 float4, 4 per thread
            const int r = t >> 3;        // 0..31
            const int q = t & 7;         // float4 slots q, q+8, q+16, q+24
            const int node = base + r;
            const int idx = (node < N) ? data[node] : 0;
            const float4* src = (const float4*)(vecs + (size_t)idx * D);
            float4* dst = (float4*)(a_s + r * D);
            #pragma unroll
            for (int m = 0; m < 4; m++) dst[q + 8 * m] = src[q + 8 * m];
        }
        __syncthreads();

        float4 acc[4];
        #pragma unroll
        for (int j = 0; j < 4; j++) acc[j] = make_float4(0.f, 0.f, 0.f, 0.f);

        #pragma unroll 4
        for (int k = 0; k < D; k++) {
            const float4 w4 = *(const float4*)(w_s + k * D + 4 * cg);
            float a0 = a_s[(ng     ) * D + k];
            float a1 = a_s[(ng +  8) * D + k];
            float a2 = a_s[(ng + 16) * D + k];
            float a3 = a_s[(ng + 24) * D + k];
            acc[0].x += a0 * w4.x; acc[0].y += a0 * w4.y; acc[0].z += a0 * w4.z; acc[0].w += a0 * w4.w;
            acc[1].x += a1 * w4.x; acc[1].y += a1 * w4.y; acc[1].z += a1 * w4.z; acc[1].w += a1 * w4.w;
            acc[2].x += a2 * w4.x; acc[2].y += a2 * w4.y; acc[2].z += a2 * w4.z; acc[2].w += a2 * w4.w;
            acc[3].x += a3 * w4.x; acc[3].y += a3 * w4.y; acc[3].z += a3 * w4.z; acc[3].w += a3 * w4.w;
        }
        #pragma unroll
        for (int j = 0; j < 4; j++) {
            const int node = base + ng + 8 * j;
            if (node < N) {
                float4 o;
                o.x = acc[j].x + b4.x; o.y = acc[j].y + b4.y;
                o.z = acc[j].z + b4.z; o.w = acc[j].w + b4.w;
                ((float4*)(X + (size_t)node * D))[cg] = o;
            }
        }
    }
}

// ---------------- one tree level ----------------
// parents [p0, p0+npar), children [c0, c0+2*npar). Block = 64-child tile.
__global__ __launch_bounds__(256) void tree_level_kernel(
    const int* __restrict__ edges,
    const float* __restrict__ edge_W,   // [8][128][128]
    const float* __restrict__ edge_b,   // [8][128]
    float* __restrict__ X,
    int p0, int npar, int c0, int leaf_children)
{
    __shared__ float w_s[D * D];     // 64KB
    __shared__ float a_s[64 * D];    // 32KB  (child ret vectors)
    __shared__ float y_s[64 * D];    // 32KB  (per-child matvec result)
    __shared__ int eid_s[64];
    __shared__ unsigned char list_s[8][64];
    __shared__ int cnt_s[8];

    const int t = threadIdx.x;
    const int tile = blockIdx.x;
    const int cbase = c0 + tile * 64;
    const int M = 2 * npar;
    const int nvalid = min(64, c0 + M - cbase);   // always even

    if (t < 64) eid_s[t] = (t < nvalid) ? edges[cbase + t] : -1;

    {   // stage child vectors (ReLU unless children are leaves)
        const int r = t >> 2;       // 0..63
        const int q = t & 3;        // float4 slots q, q+4, ..., q+28
        if (r < nvalid) {
            const float4* src = (const float4*)(X + (size_t)(cbase + r) * D);
            float4* dst = (float4*)(a_s + r * D);
            #pragma unroll
            for (int m = 0; m < 8; m++) {
                float4 v = src[q + 4 * m];
                if (!leaf_children) {
                    v.x = fmaxf(v.x, 0.f); v.y = fmaxf(v.y, 0.f);
                    v.z = fmaxf(v.z, 0.f); v.w = fmaxf(v.w, 0.f);
                }
                dst[q + 4 * m] = v;
            }
        }
    }
    __syncthreads();

    if (t < 8) {   // build per-edge-type compact lists
        int c = 0;
        #pragma unroll 8
        for (int i = 0; i < 64; i++)
            if (eid_s[i] == t) list_s[t][c++] = (unsigned char)i;
        cnt_s[t] = c;
    }
    // (covered by the sync after W staging below)

    for (int e = 0; e < 8; e++) {
        __syncthreads();   // w_s free to overwrite; also fences list build on e==0
        for (int i = t; i < D * D / 4; i += 256)
            ((float4*)w_s)[i] = ((const float4*)(edge_W + (size_t)e * D * D))[i];
        __syncthreads();

        const int cnt = cnt_s[e];
        const int pairs = (cnt + 1) >> 1;
        // item: (child-pair u, 8-col group cq) -> 2 children x 8 cols
        for (int it = t; it < pairs * 16; it += 256) {
            const int u  = it >> 4;
            const int cq = it & 15;
            const int ci0 = list_s[e][2 * u];
            const bool has1 = (2 * u + 1) < cnt;
            const int ci1 = has1 ? list_s[e][2 * u + 1] : ci0;
            float4 a00 = make_float4(0,0,0,0), a01 = make_float4(0,0,0,0);
            float4 a10 = make_float4(0,0,0,0), a11 = make_float4(0,0,0,0);
            #pragma unroll 4
            for (int k = 0; k < D; k++) {
                const float4 w0 = *(const float4*)(w_s + k * D + 8 * cq);
                const float4 w1 = *(const float4*)(w_s + k * D + 8 * cq + 4);
                const float v0 = a_s[ci0 * D + k];
                const float v1 = a_s[ci1 * D + k];
                a00.x += v0 * w0.x; a00.y += v0 * w0.y; a00.z += v0 * w0.z; a00.w += v0 * w0.w;
                a01.x += v0 * w1.x; a01.y += v0 * w1.y; a01.z += v0 * w1.z; a01.w += v0 * w1.w;
                a10.x += v1 * w0.x; a10.y += v1 * w0.y; a10.z += v1 * w0.z; a10.w += v1 * w0.w;
                a11.x += v1 * w1.x; a11.y += v1 * w1.y; a11.z += v1 * w1.z; a11.w += v1 * w1.w;
            }
            ((float4*)(y_s + ci0 * D))[2 * cq]     = a00;
            ((float4*)(y_s + ci0 * D))[2 * cq + 1] = a01;
            if (has1) {
                ((float4*)(y_s + ci1 * D))[2 * cq]     = a10;
                ((float4*)(y_s + ci1 * D))[2 * cq + 1] = a11;
            }
        }
    }
    __syncthreads();

    // combine: h = (raw + y0 + y1 + edge_b[e0] + edge_b[e1]) / 3 -> X[parent]
    const int nparents = nvalid >> 1;
    for (int it = t; it < nparents * 32; it += 256) {
        const int j  = it >> 5;      // parent local
        const int cg = it & 31;      // float4 col group
        const int p = p0 + tile * 32 + j;
        const int e0 = eid_s[2 * j];
        const int e1 = eid_s[2 * j + 1];
        const float4 y0 = ((const float4*)(y_s + (2 * j) * D))[cg];
        const float4 y1 = ((const float4*)(y_s + (2 * j + 1) * D))[cg];
        const float4 b0 = ((const float4*)(edge_b + (size_t)e0 * D))[cg];
        const float4 b1 = ((const float4*)(edge_b + (size_t)e1 * D))[cg];
        const float4 raw = ((const float4*)(X + (size_t)p * D))[cg];
        float4 h;
        const float inv3 = 1.0f / 3.0f;
        h.x = (raw.x + y0.x + y1.x + b0.x + b1.x) * inv3;
        h.y = (raw.y + y0.y + y1.y + b0.y + b1.y) * inv3;
        h.z = (raw.z + y0.z + y1.z + b0.z + b1.z) * inv3;
        h.w = (raw.w + y0.w + y1.w + b0.w + b1.w) * inv3;
        ((float4*)(X + (size_t)p * D))[cg] = h;
    }
}

// ---------------- score: out[i] = dot(X[i,:], score_W) ----------------
__global__ __launch_bounds__(256) void score_kernel(
    const float* __restrict__ X,
    const float* __restrict__ sW,
    float* __restrict__ out, int N)
{
    const int lane = threadIdx.x & 63;
    const int wave = blockIdx.x * 4 + (threadIdx.x >> 6);
    const int nw = gridDim.x * 4;
    const float s0 = sW[2 * lane];
    const float s1 = sW[2 * lane + 1];
    for (int n = wave; n < N; n += nw) {
        const float2 v = ((const float2*)(X + (size_t)n * D))[lane];
        float acc = v.x * s0 + v.y * s1;
        #pragma unroll
        for (int off = 32; off > 0; off >>= 1)
            acc += __shfl_down(acc, off, 64);
        if (lane == 0) out[n] = acc;
    }
}

extern "C" void kernel_launch(void* const* d_in, const int* in_sizes, int n_in,
                              void* d_out, int out_size, void* d_ws, size_t ws_size,
                              hipStream_t stream) {
    const int*   data      = (const int*)d_in[0];
    const int*   edges     = (const int*)d_in[1];
    const float* data_vecs = (const float*)d_in[2];
    const float* data_W    = (const float*)d_in[3];
    const float* data_b    = (const float*)d_in[4];
    const float* edge_W    = (const float*)d_in[5];
    const float* edge_b    = (const float*)d_in[6];
    const float* score_W   = (const float*)d_in[7];
    float* out = (float*)d_out;
    float* X   = (float*)d_ws;          // N*128 fp32 = 134 MB

    const int N = in_sizes[0];          // 2^18 - 1 = 262143
    const int ntiles = (N + 31) / 32;

    embed_kernel<<<1024, 256, 0, stream>>>(data, data_vecs, data_W, data_b, X, N, ntiles);

    for (int l = LVLS - 2; l >= 0; l--) {
        const int npar = 1 << l;
        const int p0 = npar - 1;
        const int c0 = 2 * npar - 1;
        const int M = 2 * npar;
        const int blocks = (M + 63) / 64;
        const int leaf_children = (l == LVLS - 2) ? 1 : 0;
        tree_level_kernel<<<blocks, 256, 0, stream>>>(
            edges, edge_W, edge_b, X, p0, npar, c0, leaf_children);
    }

    score_kernel<<<1024, 256, 0, stream>>>(X, score_W, out, N);
}

// Round 2
// 633.639 us; speedup vs baseline: 3.0622x; 3.0622x over previous
//
#include <hip/hip_runtime.h>

#define D 128
#define NLVL 17          // parent levels 0..16
#define LVLPAD 256       // per-level perm slack for group padding (8 groups x 32)

__device__ __forceinline__ int lvl_base_dev(int l) { return ((2 << l) - 2) + LVLPAD * l; }

// ============ sort step 1: per-(level,edge) counts ============
__global__ __launch_bounds__(256) void count_kernel(
    const int* __restrict__ edges, int* __restrict__ gcnt, int Nn)
{
    __shared__ int lc[NLVL * 8];
    const int t = threadIdx.x;
    for (int i = t; i < NLVL * 8; i += 256) lc[i] = 0;
    __syncthreads();
    for (int c = 1 + blockIdx.x * 256 + t; c < Nn; c += gridDim.x * 256) {
        const int e = edges[c];
        const int p = (c - 1) >> 1;
        const int l = 31 - __clz(p + 1);
        atomicAdd(&lc[l * 8 + e], 1);
    }
    __syncthreads();
    for (int i = t; i < NLVL * 8; i += 256) if (lc[i]) atomicAdd(&gcnt[i], lc[i]);
}

// ============ sort step 2: padded prefix (+ sv = data_W @ score_W, s0 = data_b . score_W) ============
__global__ __launch_bounds__(256) void prefix_sv_kernel(
    const int* __restrict__ gcnt, int* __restrict__ gstart,
    const float* __restrict__ dW, const float* __restrict__ db,
    const float* __restrict__ sWs, float* __restrict__ sv, float* __restrict__ s0)
{
    __shared__ float red[256];
    const int t = threadIdx.x;
    if (t < D) {
        float acc = 0.f;
        for (int j = 0; j < D; j++) acc += dW[t * D + j] * sWs[j];
        sv[t] = acc;
    }
    red[t] = (t < D) ? db[t] * sWs[t] : 0.f;
    __syncthreads();
    for (int s = 128; s > 0; s >>= 1) { if (t < s) red[t] += red[t + s]; __syncthreads(); }
    if (t == 0) {
        *s0 = red[0];
        for (int l = 0; l < NLVL; l++) {
            int acc = 0;
            for (int e = 0; e < 8; e++) {
                gstart[l * 9 + e] = acc;
                acc = (acc + gcnt[l * 8 + e] + 31) & ~31;   // pad group to 32
            }
            gstart[l * 9 + 8] = acc;
        }
    }
}

// ============ sort step 3: placement ============
#define CHUNK 2048
__global__ __launch_bounds__(256) void place_kernel(
    const int* __restrict__ edges, const int* __restrict__ gstart,
    int* __restrict__ ctr, int* __restrict__ perm, int Nn)
{
    __shared__ unsigned char key_s[CHUNK];
    __shared__ int lcnt[NLVL * 8], lbase[NLVL * 8];
    __shared__ int gs_s[NLVL * 9];
    const int t = threadIdx.x;
    for (int i = t; i < NLVL * 8; i += 256) lcnt[i] = 0;
    for (int i = t; i < NLVL * 9; i += 256) gs_s[i] = gstart[i];
    const int base = 1 + blockIdx.x * CHUNK;
    __syncthreads();
    for (int i = t; i < CHUNK; i += 256) {
        const int c = base + i;
        if (c < Nn) {
            const int e = edges[c];
            const int p = (c - 1) >> 1;
            const int l = 31 - __clz(p + 1);
            const int k = l * 8 + e;
            key_s[i] = (unsigned char)k;
            atomicAdd(&lcnt[k], 1);
        } else key_s[i] = 255;
    }
    __syncthreads();
    for (int i = t; i < NLVL * 8; i += 256) {
        const int n = lcnt[i];
        lbase[i] = n ? atomicAdd(&ctr[i], n) : 0;
        lcnt[i] = 0;
    }
    __syncthreads();
    for (int i = t; i < CHUNK; i += 256) {
        const int c = base + i;
        if (c >= Nn) continue;
        const int k = key_s[i];
        const int off = atomicAdd(&lcnt[k], 1);
        const int l = k >> 3, e = k & 7;
        const int pos = gs_s[l * 9 + e] + lbase[k] + off;
        perm[lvl_base_dev(l) + pos] = c;
    }
}

// ============ compose: C_e = data_W @ edge_W[e], d_e = data_b @ edge_W[e] + edge_b[e] ============
__global__ __launch_bounds__(256) void compose_kernel(
    const float* __restrict__ dW, const float* __restrict__ db,
    const float* __restrict__ eW, const float* __restrict__ eb,
    float* __restrict__ C, float* __restrict__ dv)
{
    __shared__ float aw_s[D * D];     // 64KB: data_W
    __shared__ float w_s[D * 32];     // 16KB: edge_W[e] col slice
    const int t = threadIdx.x;
    const int e = blockIdx.x >> 2, cc = blockIdx.x & 3;   // cols 32*cc..
    for (int i = t; i < D * D / 4; i += 256) ((float4*)aw_s)[i] = ((const float4*)dW)[i];
    for (int i = t; i < D * 8; i += 256) {
        const int k = i >> 3, j4 = i & 7;
        ((float4*)w_s)[i] = ((const float4*)eW)[((size_t)e * D + k) * 32 + cc * 8 + j4];
    }
    __syncthreads();
    const int r2 = t >> 1, h = t & 1;   // row r2, 16 cols = h*16..
    float4 acc[4];
    #pragma unroll
    for (int m = 0; m < 4; m++) acc[m] = make_float4(0.f, 0.f, 0.f, 0.f);
    for (int k = 0; k < D; k++) {
        const float a = aw_s[r2 * D + k];
        #pragma unroll
        for (int m = 0; m < 4; m++) {
            const float4 w4 = ((const float4*)w_s)[k * 8 + h * 4 + m];
            acc[m].x += a * w4.x; acc[m].y += a * w4.y; acc[m].z += a * w4.z; acc[m].w += a * w4.w;
        }
    }
    #pragma unroll
    for (int m = 0; m < 4; m++)
        ((float4*)C)[((size_t)e * D + r2) * 32 + cc * 8 + h * 4 + m] = acc[m];
    if (t < 32) {
        float a2 = 0.f;
        for (int k = 0; k < D; k++) a2 += db[k] * w_s[k * 32 + t];
        dv[e * D + cc * 32 + t] = a2 + eb[e * D + cc * 32 + t];
    }
}

// ============ embed (internal nodes only): X[i] = vecs[data[i]] @ data_W + data_b ============
__global__ __launch_bounds__(256) void embed_kernel(
    const int* __restrict__ data, const float* __restrict__ vecs,
    const float* __restrict__ W, const float* __restrict__ b,
    float* __restrict__ X, int NI, int ntiles)
{
    __shared__ float w_s[D * D];    // 64KB
    __shared__ float a_s[32 * D];   // 16KB
    const int t = threadIdx.x;
    for (int i = t; i < D * D / 4; i += 256)
        ((float4*)w_s)[i] = ((const float4*)W)[i];
    const int cg = t & 31;
    const int ng = t >> 5;
    const float4 b4 = ((const float4*)b)[cg];
    for (int tile = blockIdx.x; tile < ntiles; tile += gridDim.x) {
        const int base = tile * 32;
        __syncthreads();
        {
            const int r = t >> 3, q = t & 7;
            const int node = base + r;
            const int idx = (node < NI) ? data[node] : 0;
            const float4* src = (const float4*)(vecs + (size_t)idx * D);
            float4* dst = (float4*)(a_s + r * D);
            #pragma unroll
            for (int m = 0; m < 4; m++) dst[q + 8 * m] = src[q + 8 * m];
        }
        __syncthreads();
        float4 acc[4];
        #pragma unroll
        for (int j = 0; j < 4; j++) acc[j] = make_float4(0.f, 0.f, 0.f, 0.f);
        #pragma unroll 4
        for (int k = 0; k < D; k++) {
            const float4 w4 = *(const float4*)(w_s + k * D + 4 * cg);
            const float a0 = a_s[(ng     ) * D + k];
            const float a1 = a_s[(ng +  8) * D + k];
            const float a2 = a_s[(ng + 16) * D + k];
            const float a3 = a_s[(ng + 24) * D + k];
            acc[0].x += a0 * w4.x; acc[0].y += a0 * w4.y; acc[0].z += a0 * w4.z; acc[0].w += a0 * w4.w;
            acc[1].x += a1 * w4.x; acc[1].y += a1 * w4.y; acc[1].z += a1 * w4.z; acc[1].w += a1 * w4.w;
            acc[2].x += a2 * w4.x; acc[2].y += a2 * w4.y; acc[2].z += a2 * w4.z; acc[2].w += a2 * w4.w;
            acc[3].x += a3 * w4.x; acc[3].y += a3 * w4.y; acc[3].z += a3 * w4.z; acc[3].w += a3 * w4.w;
        }
        #pragma unroll
        for (int j = 0; j < 4; j++) {
            const int node = base + ng + 8 * j;
            if (node < NI) {
                float4 o;
                o.x = acc[j].x + b4.x; o.y = acc[j].y + b4.y;
                o.z = acc[j].z + b4.z; o.w = acc[j].w + b4.w;
                ((float4*)(X + (size_t)node * D))[cg] = o;
            }
        }
    }
}

// ============ tree GEMM: one 32-row tile of one edge group; fused child scoring ============
// internal: rows = ReLU(X[c]) (score uses pre-ReLU), W=edge_W[e], b=edge_b[e]
// leaf:     rows = vecs[data[c]] (composed), W=C_e, b=d_e, score = row.sv + s0
// epilogue overwrites X[c] with y (+bias).
__global__ __launch_bounds__(256, 2) void tree_gemm_kernel(
    float* X,
    const float* rowsrc,
    const int* __restrict__ data,
    const int* __restrict__ perm,
    const int* __restrict__ gstart9,
    const float* __restrict__ Wbase,
    const float* __restrict__ Bbase,
    const float* __restrict__ svec,
    const float* __restrict__ s0p,
    float* __restrict__ out,
    int lbase, int leaf)
{
    __shared__ float w_s[D * D];    // 64KB
    __shared__ float a_s[32 * D];   // 16KB  -> exactly 80KB total
    const int t = threadIdx.x;
    const int ts = blockIdx.x * 32;
    const int total = gstart9[8];
    if (ts >= total) return;
    int e = 0;
    #pragma unroll
    for (int j = 1; j < 8; j++) if (ts >= gstart9[j]) e = j;

    const float4* Wg = (const float4*)(Wbase + (size_t)e * D * D);
    for (int i = t; i < D * D / 4; i += 256) ((float4*)w_s)[i] = Wg[i];

    {   // stage rows + fused score
        const int r = t >> 3, q = t & 7;
        const int c = perm[lbase + ts + r];
        float4* dst = (float4*)(a_s + r * D);
        if (c >= 0) {
            const float* srow = leaf ? (rowsrc + (size_t)data[c] * D)
                                     : (rowsrc + (size_t)c * D);
            const float4* src = (const float4*)srow;
            float sc = 0.f;
            #pragma unroll
            for (int m = 0; m < 4; m++) {
                float4 v = src[q + 8 * m];
                const float4 s4 = ((const float4*)svec)[q + 8 * m];
                sc += v.x * s4.x + v.y * s4.y + v.z * s4.z + v.w * s4.w;
                if (!leaf) {
                    v.x = fmaxf(v.x, 0.f); v.y = fmaxf(v.y, 0.f);
                    v.z = fmaxf(v.z, 0.f); v.w = fmaxf(v.w, 0.f);
                }
                dst[q + 8 * m] = v;
            }
            sc += __shfl_xor(sc, 1, 64);
            sc += __shfl_xor(sc, 2, 64);
            sc += __shfl_xor(sc, 4, 64);
            if (q == 0) out[c] = leaf ? (sc + s0p[0]) : sc;
        } else {
            const float4 z = make_float4(0.f, 0.f, 0.f, 0.f);
            #pragma unroll
            for (int m = 0; m < 4; m++) dst[q + 8 * m] = z;
        }
    }
    __syncthreads();

    const int cg = t & 31;
    const int ng = t >> 5;
    float4 acc[4];
    #pragma unroll
    for (int j = 0; j < 4; j++) acc[j] = make_float4(0.f, 0.f, 0.f, 0.f);
    #pragma unroll 4
    for (int k = 0; k < D; k++) {
        const float4 w4 = *(const float4*)(w_s + k * D + 4 * cg);
        const float a0 = a_s[(ng     ) * D + k];
        const float a1 = a_s[(ng +  8) * D + k];
        const float a2 = a_s[(ng + 16) * D + k];
        const float a3 = a_s[(ng + 24) * D + k];
        acc[0].x += a0 * w4.x; acc[0].y += a0 * w4.y; acc[0].z += a0 * w4.z; acc[0].w += a0 * w4.w;
        acc[1].x += a1 * w4.x; acc[1].y += a1 * w4.y; acc[1].z += a1 * w4.z; acc[1].w += a1 * w4.w;
        acc[2].x += a2 * w4.x; acc[2].y += a2 * w4.y; acc[2].z += a2 * w4.z; acc[2].w += a2 * w4.w;
        acc[3].x += a3 * w4.x; acc[3].y += a3 * w4.y; acc[3].z += a3 * w4.z; acc[3].w += a3 * w4.w;
    }
    const float4 b4 = ((const float4*)(Bbase + (size_t)e * D))[cg];
    #pragma unroll
    for (int j = 0; j < 4; j++) {
        const int row = ng + 8 * j;
        const int c = perm[lbase + ts + row];
        if (c >= 0) {
            float4 o;
            o.x = acc[j].x + b4.x; o.y = acc[j].y + b4.y;
            o.z = acc[j].z + b4.z; o.w = acc[j].w + b4.w;
            ((float4*)(X + (size_t)c * D))[cg] = o;
        }
    }
}

// ============ combine: X[p] = (X[p] + y0 + y1)/3 ; root also scored ============
__global__ __launch_bounds__(256) void combine_kernel(
    float* X, const float* __restrict__ sWs, float* __restrict__ out,
    int p0, int npar, int c0, int root)
{
    const float inv3 = 1.0f / 3.0f;
    const int items = npar * 32;
    for (int it = blockIdx.x * 256 + threadIdx.x; it < items; it += gridDim.x * 256) {
        const int j = it >> 5, cg = it & 31;
        const size_t p = (size_t)(p0 + j);
        float4 raw = ((const float4*)(X + p * D))[cg];
        const float4 y0 = ((const float4*)(X + (size_t)(c0 + 2 * j) * D))[cg];
        const float4 y1 = ((const float4*)(X + (size_t)(c0 + 2 * j + 1) * D))[cg];
        float4 h;
        h.x = (raw.x + y0.x + y1.x) * inv3;
        h.y = (raw.y + y0.y + y1.y) * inv3;
        h.z = (raw.z + y0.z + y1.z) * inv3;
        h.w = (raw.w + y0.w + y1.w) * inv3;
        ((float4*)(X + p * D))[cg] = h;
        if (root) {
            const float4 s4 = ((const float4*)sWs)[cg];
            float sc = h.x * s4.x + h.y * s4.y + h.z * s4.z + h.w * s4.w;
            sc += __shfl_xor(sc, 1, 64);
            sc += __shfl_xor(sc, 2, 64);
            sc += __shfl_xor(sc, 4, 64);
            sc += __shfl_xor(sc, 8, 64);
            sc += __shfl_xor(sc, 16, 64);
            if (cg == 0) out[0] = sc;
        }
    }
}

extern "C" void kernel_launch(void* const* d_in, const int* in_sizes, int n_in,
                              void* d_out, int out_size, void* d_ws, size_t ws_size,
                              hipStream_t stream) {
    const int*   data      = (const int*)d_in[0];
    const int*   edges     = (const int*)d_in[1];
    const float* data_vecs = (const float*)d_in[2];
    const float* data_W    = (const float*)d_in[3];
    const float* data_b    = (const float*)d_in[4];
    const float* edge_W    = (const float*)d_in[5];
    const float* edge_b    = (const float*)d_in[6];
    const float* score_W   = (const float*)d_in[7];
    float* out = (float*)d_out;

    const int Nn = in_sizes[0];          // 2^18 - 1
    const int NI = Nn >> 1;              // internal nodes: 2^17 - 1
    const int PERM_TOTAL = (Nn - 1) + LVLPAD * NLVL;

    char* w = (char*)d_ws;
    size_t off = 0;
    float* X = (float*)(w + off); off += (size_t)Nn * D * 4;            // full rows; leaf rows hold y only
    int* perm = (int*)(w + off);  off += (size_t)PERM_TOTAL * 4;
    off = (off + 255) & ~(size_t)255;
    int* gstart = (int*)(w + off); off += NLVL * 9 * 4;
    int* gcnt   = (int*)(w + off); off += NLVL * 8 * 4;
    int* ctr    = (int*)(w + off); off += NLVL * 8 * 4;
    off = (off + 255) & ~(size_t)255;
    float* Ccomp = (float*)(w + off); off += (size_t)8 * D * D * 4;
    float* dcomp = (float*)(w + off); off += 8 * D * 4;
    float* sv    = (float*)(w + off); off += D * 4;
    float* s0    = (float*)(w + off); off += 4;

    hipMemsetAsync(perm, 0xFF, (size_t)PERM_TOTAL * 4, stream);
    hipMemsetAsync(gstart, 0, (size_t)(NLVL * 9 + NLVL * 8 + NLVL * 8) * 4, stream);

    count_kernel<<<128, 256, 0, stream>>>(edges, gcnt, Nn);
    prefix_sv_kernel<<<1, 256, 0, stream>>>(gcnt, gstart, data_W, data_b, score_W, sv, s0);
    place_kernel<<<(Nn - 1 + CHUNK - 1) / CHUNK, 256, 0, stream>>>(edges, gstart, ctr, perm, Nn);
    compose_kernel<<<32, 256, 0, stream>>>(data_W, data_b, edge_W, edge_b, Ccomp, dcomp);
    embed_kernel<<<1024, 256, 0, stream>>>(data, data_vecs, data_W, data_b, X, NI, (NI + 31) / 32);

    for (int l = NLVL - 1; l >= 0; l--) {
        const int npar = 1 << l;
        const int p0 = npar - 1;
        const int c0 = 2 * npar - 1;
        const int M = 2 * npar;
        const int lbase = ((2 << l) - 2) + LVLPAD * l;
        const int gblocks = M / 32 + 8;
        const int leaf = (l == NLVL - 1) ? 1 : 0;
        tree_gemm_kernel<<<gblocks, 256, 0, stream>>>(
            X,
            leaf ? data_vecs : (const float*)X,
            data, perm, gstart + l * 9,
            leaf ? Ccomp : edge_W,
            leaf ? dcomp : edge_b,
            leaf ? sv : score_W,
            s0, out, lbase, leaf);
        const int items = npar * 32;
        const int cblocks = (items + 255) / 256;
        combine_kernel<<<(cblocks < 4096 ? cblocks : 4096), 256, 0, stream>>>(
            X, score_W, out, p0, npar, c0, (l == 0) ? 1 : 0);
    }
}

// Round 4
// 384.428 us; speedup vs baseline: 5.0473x; 1.6483x over previous
//
#include <hip/hip_runtime.h>

#define D 128
#define NLVL 17          // parent levels 0..16
#define TS 128           // rows per GEMM tile
#define LVLPAD 1024      // per-level perm slack: 8 groups x 128 pad
#define LDSTR 136        // LDS row stride in bf16 elems (272B: bank-conflict-free b128)

typedef float  floatx4 __attribute__((ext_vector_type(4)));
typedef short  shortx8 __attribute__((ext_vector_type(8)));

__device__ __forceinline__ unsigned short f2bf(float f) {   // RNE fp32->bf16
    unsigned u = __float_as_uint(f);
    u += 0x7FFFu + ((u >> 16) & 1u);
    return (unsigned short)(u >> 16);
}
__device__ __forceinline__ float bf2f(unsigned short h) {
    return __uint_as_float(((unsigned)h) << 16);
}
__device__ __forceinline__ int lvl_base_dev(int l) { return ((2 << l) - 2) + LVLPAD * l; }

// ============ sort step 1: per-(level,edge) counts ============
__global__ __launch_bounds__(256) void count_kernel(
    const int* __restrict__ edges, int* __restrict__ gcnt, int Nn)
{
    __shared__ int lc[NLVL * 8];
    const int t = threadIdx.x;
    for (int i = t; i < NLVL * 8; i += 256) lc[i] = 0;
    __syncthreads();
    for (int c = 1 + blockIdx.x * 256 + t; c < Nn; c += gridDim.x * 256) {
        const int e = edges[c];
        const int p = (c - 1) >> 1;
        const int l = 31 - __clz(p + 1);
        atomicAdd(&lc[l * 8 + e], 1);
    }
    __syncthreads();
    for (int i = t; i < NLVL * 8; i += 256) if (lc[i]) atomicAdd(&gcnt[i], lc[i]);
}

// ============ sort step 2: padded prefix (+ sv = data_W @ score_W, s0 = data_b . score_W) ============
__global__ __launch_bounds__(256) void prefix_sv_kernel(
    const int* __restrict__ gcnt, int* __restrict__ gstart,
    const float* __restrict__ dW, const float* __restrict__ db,
    const float* __restrict__ sWs, float* __restrict__ sv, float* __restrict__ s0)
{
    __shared__ float red[256];
    const int t = threadIdx.x;
    if (t < D) {
        float acc = 0.f;
        for (int j = 0; j < D; j++) acc += dW[t * D + j] * sWs[j];
        sv[t] = acc;
    }
    red[t] = (t < D) ? db[t] * sWs[t] : 0.f;
    __syncthreads();
    for (int s = 128; s > 0; s >>= 1) { if (t < s) red[t] += red[t + s]; __syncthreads(); }
    if (t == 0) {
        *s0 = red[0];
        for (int l = 0; l < NLVL; l++) {
            int acc = 0;
            for (int e = 0; e < 8; e++) {
                gstart[l * 9 + e] = acc;
                acc = (acc + gcnt[l * 8 + e] + (TS - 1)) & ~(TS - 1);   // pad group to 128
            }
            gstart[l * 9 + 8] = acc;
        }
    }
}

// ============ sort step 3: placement ============
#define CHUNK 2048
__global__ __launch_bounds__(256) void place_kernel(
    const int* __restrict__ edges, const int* __restrict__ gstart,
    int* __restrict__ ctr, int* __restrict__ perm, int Nn)
{
    __shared__ unsigned char key_s[CHUNK];
    __shared__ int lcnt[NLVL * 8], lbase[NLVL * 8];
    __shared__ int gs_s[NLVL * 9];
    const int t = threadIdx.x;
    for (int i = t; i < NLVL * 8; i += 256) lcnt[i] = 0;
    for (int i = t; i < NLVL * 9; i += 256) gs_s[i] = gstart[i];
    const int base = 1 + blockIdx.x * CHUNK;
    __syncthreads();
    for (int i = t; i < CHUNK; i += 256) {
        const int c = base + i;
        if (c < Nn) {
            const int e = edges[c];
            const int p = (c - 1) >> 1;
            const int l = 31 - __clz(p + 1);
            const int k = l * 8 + e;
            key_s[i] = (unsigned char)k;
            atomicAdd(&lcnt[k], 1);
        } else key_s[i] = 255;
    }
    __syncthreads();
    for (int i = t; i < NLVL * 8; i += 256) {
        const int n = lcnt[i];
        lbase[i] = n ? atomicAdd(&ctr[i], n) : 0;
        lcnt[i] = 0;
    }
    __syncthreads();
    for (int i = t; i < CHUNK; i += 256) {
        const int c = base + i;
        if (c >= Nn) continue;
        const int k = key_s[i];
        const int off = atomicAdd(&lcnt[k], 1);
        const int l = k >> 3, e = k & 7;
        const int pos = gs_s[l * 9 + e] + lbase[k] + off;
        perm[lvl_base_dev(l) + pos] = c;
    }
}

// ============ compose: Ccomp_e = data_W @ edge_W[e] (fp32), dcomp_e = data_b @ edge_W[e] + edge_b[e] ============
__global__ __launch_bounds__(256) void compose_kernel(
    const float* __restrict__ dW, const float* __restrict__ db,
    const float* __restrict__ eW, const float* __restrict__ eb,
    float* __restrict__ C, float* __restrict__ dv)
{
    __shared__ float aw_s[D * D];     // 64KB: data_W
    __shared__ float w_s[D * 32];     // 16KB: edge_W[e] col slice
    const int t = threadIdx.x;
    const int e = blockIdx.x >> 2, cc = blockIdx.x & 3;   // cols 32*cc..
    for (int i = t; i < D * D / 4; i += 256) ((float4*)aw_s)[i] = ((const float4*)dW)[i];
    for (int i = t; i < D * 8; i += 256) {
        const int k = i >> 3, j4 = i & 7;
        ((float4*)w_s)[i] = ((const float4*)eW)[((size_t)e * D + k) * 32 + cc * 8 + j4];
    }
    __syncthreads();
    const int r2 = t >> 1, h = t & 1;   // row r2, 16 cols = h*16..
    float4 acc[4];
    #pragma unroll
    for (int m = 0; m < 4; m++) acc[m] = make_float4(0.f, 0.f, 0.f, 0.f);
    for (int k = 0; k < D; k++) {
        const float a = aw_s[r2 * D + k];
        #pragma unroll
        for (int m = 0; m < 4; m++) {
            const float4 w4 = ((const float4*)w_s)[k * 8 + h * 4 + m];
            acc[m].x += a * w4.x; acc[m].y += a * w4.y; acc[m].z += a * w4.z; acc[m].w += a * w4.w;
        }
    }
    #pragma unroll
    for (int m = 0; m < 4; m++)
        ((float4*)C)[((size_t)e * D + r2) * 32 + cc * 8 + h * 4 + m] = acc[m];
    if (t < 32) {
        float a2 = 0.f;
        for (int k = 0; k < D; k++) a2 += db[k] * w_s[k * 32 + t];
        dv[e * D + cc * 32 + t] = a2 + eb[e * D + cc * 32 + t];
    }
}

// ============ convert+transpose weights to bf16 [n][k] ============
// block b: 0..7 -> ewt[b] from edge_W[b]; 8..15 -> cwt[b-8] from Ccomp; 16 -> dwt from data_W
__global__ __launch_bounds__(256) void convert_kernel(
    const float* __restrict__ eW, const float* __restrict__ Ccomp,
    const float* __restrict__ dW,
    unsigned short* __restrict__ ewt, unsigned short* __restrict__ cwt,
    unsigned short* __restrict__ dwt)
{
    __shared__ float lds[D * 129];
    const int b = blockIdx.x;
    const float* src = (b < 8) ? (eW + (size_t)b * D * D)
                     : (b < 16) ? (Ccomp + (size_t)(b - 8) * D * D)
                     : dW;
    unsigned short* dst = (b < 8) ? (ewt + (size_t)b * D * D)
                        : (b < 16) ? (cwt + (size_t)(b - 8) * D * D)
                        : dwt;
    const int t = threadIdx.x;
    for (int i = t; i < D * D / 4; i += 256) {
        float4 v = ((const float4*)src)[i];
        const int k = (i * 4) >> 7, n = (i * 4) & 127;
        lds[k * 129 + n]     = v.x;
        lds[k * 129 + n + 1] = v.y;
        lds[k * 129 + n + 2] = v.z;
        lds[k * 129 + n + 3] = v.w;
    }
    __syncthreads();
    const int n = t >> 1, h = t & 1;   // out row n, k-half h
    for (int k = 0; k < 64; k++)
        dst[(size_t)n * D + h * 64 + k] = f2bf(lds[(h * 64 + k) * 129 + n]);
}

// ============ embed (internal nodes): X[i] = bf16( vecs[data[i]] @ data_W + data_b ) ============
__global__ __launch_bounds__(256, 2) void embed_kernel(
    const int* __restrict__ data, const float* __restrict__ vecs,
    const unsigned short* __restrict__ dwt, const float* __restrict__ db,
    unsigned short* __restrict__ X, int NI)
{
    __shared__ unsigned short w_s[D * LDSTR];
    __shared__ unsigned short a_s[TS * LDSTR];
    const int t = threadIdx.x;
    const int base = blockIdx.x * TS;
    {   // stage W (bf16 [n][k], straight copy)
        const int r = t >> 1, h = t & 1;
        const uint4* src = (const uint4*)(dwt + (size_t)r * D + h * 64);
        uint4* dst = (uint4*)(w_s + r * LDSTR + h * 64);
        #pragma unroll
        for (int j = 0; j < 8; j++) dst[j] = src[j];
    }
    {   // stage A: gather fp32 -> bf16
        const int r = t >> 1, h = t & 1;
        const int node = base + r;
        unsigned short* dst = a_s + r * LDSTR + h * 64;
        if (node < NI) {
            const int idx = data[node];
            const float4* src = (const float4*)(vecs + (size_t)idx * D + h * 64);
            #pragma unroll
            for (int j = 0; j < 16; j++) {
                float4 v = src[j];
                uint2 o;
                o.x = (unsigned)f2bf(v.x) | ((unsigned)f2bf(v.y) << 16);
                o.y = (unsigned)f2bf(v.z) | ((unsigned)f2bf(v.w) << 16);
                ((uint2*)dst)[j] = o;
            }
        } else {
            #pragma unroll
            for (int j = 0; j < 16; j++) ((uint2*)dst)[j] = make_uint2(0u, 0u);
        }
    }
    __syncthreads();
    const int lane = t & 63, wv = t >> 6;
    const int cq = lane & 15, q = lane >> 4;
    const floatx4 z4 = {0.f, 0.f, 0.f, 0.f};
    floatx4 acc[8][2];
    #pragma unroll
    for (int i = 0; i < 8; i++) { acc[i][0] = z4; acc[i][1] = z4; }
    #pragma unroll
    for (int ks = 0; ks < 4; ks++) {
        shortx8 bfr[2];
        #pragma unroll
        for (int nl = 0; nl < 2; nl++) {
            const int n = (wv * 2 + nl) * 16 + cq;
            bfr[nl] = *(const shortx8*)(w_s + n * LDSTR + ks * 32 + q * 8);
        }
        #pragma unroll
        for (int mt = 0; mt < 8; mt++) {
            const shortx8 af = *(const shortx8*)(a_s + (mt * 16 + cq) * LDSTR + ks * 32 + q * 8);
            acc[mt][0] = __builtin_amdgcn_mfma_f32_16x16x32_bf16(af, bfr[0], acc[mt][0], 0, 0, 0);
            acc[mt][1] = __builtin_amdgcn_mfma_f32_16x16x32_bf16(af, bfr[1], acc[mt][1], 0, 0, 0);
        }
    }
    __syncthreads();
    #pragma unroll
    for (int nl = 0; nl < 2; nl++) {
        const int n = (wv * 2 + nl) * 16 + cq;
        const float bn = db[n];
        #pragma unroll
        for (int mt = 0; mt < 8; mt++) {
            #pragma unroll
            for (int r = 0; r < 4; r++) {
                const int m = mt * 16 + q * 4 + r;
                a_s[m * LDSTR + n] = f2bf(acc[mt][nl][r] + bn);
            }
        }
    }
    __syncthreads();
    {
        const int r = t >> 1, h = t & 1;
        const int node = base + r;
        if (node < NI) {
            uint4* dst = (uint4*)(X + (size_t)node * D + h * 64);
            const uint4* srcl = (const uint4*)(a_s + r * LDSTR + h * 64);
            #pragma unroll
            for (int j = 0; j < 8; j++) dst[j] = srcl[j];   // FIX: 8 uint4 = 64 bf16 (was 4)
        }
    }
}

// ============ tree GEMM (fused combine + score): 128-row tile of one edge group ============
// leaf: rows = bf16(vecs[data[c]]), W=cwt[e], bias=dcomp[e], score = row.sv + s0
// internal: h = (X[c] + X[2c+1] + X[2c+2])/3 (bf16 in, fp32 math), score = h.score_W,
//           rows = ReLU(h).  Epilogue: X[c] = rows @ W^T(bf16) + bias.
__global__ __launch_bounds__(256, 2) void tree_gemm_kernel(
    unsigned short* __restrict__ X,
    const float* __restrict__ vecs,
    const int* __restrict__ data,
    const int* __restrict__ perm,
    const int* __restrict__ gstart9,
    const unsigned short* __restrict__ Wt,   // [8][n][k] bf16
    const float* __restrict__ Bb,            // [8][128] fp32 bias
    const float* __restrict__ svec, const float* __restrict__ s0p,
    float* __restrict__ out,
    int lbase, int leaf)
{
    __shared__ unsigned short w_s[D * LDSTR];
    __shared__ unsigned short a_s[TS * LDSTR];
    __shared__ int prm[TS];
    const int t = threadIdx.x;
    const int ts = blockIdx.x * TS;
    if (ts >= gstart9[8]) return;
    int e = 0;
    #pragma unroll
    for (int j = 1; j < 8; j++) if (ts >= gstart9[j]) e = j;
    if (t < TS) prm[t] = perm[lbase + ts + t];
    {   // stage W
        const int r = t >> 1, h = t & 1;
        const uint4* src = (const uint4*)(Wt + (size_t)e * D * D + (size_t)r * D + h * 64);
        uint4* dst = (uint4*)(w_s + r * LDSTR + h * 64);
        #pragma unroll
        for (int j = 0; j < 8; j++) dst[j] = src[j];
    }
    __syncthreads();
    {   // stage A + fused combine + score
        const int r = t >> 1, h = t & 1;
        const int c = prm[r];
        unsigned short* dst = a_s + r * LDSTR + h * 64;
        if (c >= 0) {
            float sc = 0.f;
            if (leaf) {
                const float4* src = (const float4*)(vecs + (size_t)data[c] * D + h * 64);
                #pragma unroll
                for (int j = 0; j < 16; j++) {
                    float4 v = src[j];
                    const float4 s4 = ((const float4*)svec)[h * 16 + j];
                    sc += v.x * s4.x + v.y * s4.y + v.z * s4.z + v.w * s4.w;
                    uint2 o;
                    o.x = (unsigned)f2bf(v.x) | ((unsigned)f2bf(v.y) << 16);
                    o.y = (unsigned)f2bf(v.z) | ((unsigned)f2bf(v.w) << 16);
                    ((uint2*)dst)[j] = o;
                }
            } else {
                const uint4* xr = (const uint4*)(X + (size_t)c * D + h * 64);
                const uint4* ya = (const uint4*)(X + (size_t)(2 * c + 1) * D + h * 64);
                const uint4* yb = (const uint4*)(X + (size_t)(2 * c + 2) * D + h * 64);
                const float inv3 = 1.0f / 3.0f;
                #pragma unroll
                for (int j = 0; j < 8; j++) {   // 8 bf16 per uint4
                    uint4 ra = xr[j], rb = ya[j], rc = yb[j];
                    const unsigned* pa = (const unsigned*)&ra;
                    const unsigned* pb = (const unsigned*)&rb;
                    const unsigned* pc = (const unsigned*)&rc;
                    unsigned ou[4];
                    #pragma unroll
                    for (int u = 0; u < 4; u++) {
                        const float h0 = (bf2f((unsigned short)pa[u]) + bf2f((unsigned short)pb[u])
                                        + bf2f((unsigned short)pc[u])) * inv3;
                        const float h1 = (bf2f((unsigned short)(pa[u] >> 16)) + bf2f((unsigned short)(pb[u] >> 16))
                                        + bf2f((unsigned short)(pc[u] >> 16))) * inv3;
                        const int n = h * 64 + j * 8 + u * 2;
                        sc += h0 * svec[n] + h1 * svec[n + 1];
                        unsigned short q0 = f2bf(h0), q1 = f2bf(h1);
                        q0 = (q0 & 0x8000u) ? 0 : q0;   // ReLU for the matvec input
                        q1 = (q1 & 0x8000u) ? 0 : q1;
                        ou[u] = (unsigned)q0 | ((unsigned)q1 << 16);
                    }
                    ((uint4*)dst)[j] = make_uint4(ou[0], ou[1], ou[2], ou[3]);
                }
            }
            sc += __shfl_xor(sc, 1, 64);
            if (h == 0) out[c] = leaf ? (sc + s0p[0]) : sc;   // FIX: s0 added once, post-reduction
        } else {
            #pragma unroll
            for (int j = 0; j < 8; j++) ((uint4*)dst)[j] = make_uint4(0u, 0u, 0u, 0u);
        }
    }
    __syncthreads();
    const int lane = t & 63, wv = t >> 6;
    const int cq = lane & 15, q = lane >> 4;
    const floatx4 z4 = {0.f, 0.f, 0.f, 0.f};
    floatx4 acc[8][2];
    #pragma unroll
    for (int i = 0; i < 8; i++) { acc[i][0] = z4; acc[i][1] = z4; }
    #pragma unroll
    for (int ks = 0; ks < 4; ks++) {
        shortx8 bfr[2];
        #pragma unroll
        for (int nl = 0; nl < 2; nl++) {
            const int n = (wv * 2 + nl) * 16 + cq;
            bfr[nl] = *(const shortx8*)(w_s + n * LDSTR + ks * 32 + q * 8);
        }
        #pragma unroll
        for (int mt = 0; mt < 8; mt++) {
            const shortx8 af = *(const shortx8*)(a_s + (mt * 16 + cq) * LDSTR + ks * 32 + q * 8);
            acc[mt][0] = __builtin_amdgcn_mfma_f32_16x16x32_bf16(af, bfr[0], acc[mt][0], 0, 0, 0);
            acc[mt][1] = __builtin_amdgcn_mfma_f32_16x16x32_bf16(af, bfr[1], acc[mt][1], 0, 0, 0);
        }
    }
    __syncthreads();
    const float* be = Bb + (size_t)e * D;
    #pragma unroll
    for (int nl = 0; nl < 2; nl++) {
        const int n = (wv * 2 + nl) * 16 + cq;
        const float bn = be[n];
        #pragma unroll
        for (int mt = 0; mt < 8; mt++) {
            #pragma unroll
            for (int r = 0; r < 4; r++) {
                const int m = mt * 16 + q * 4 + r;
                a_s[m * LDSTR + n] = f2bf(acc[mt][nl][r] + bn);
            }
        }
    }
    __syncthreads();
    {
        const int r = t >> 1, h = t & 1;
        const int c = prm[r];
        if (c >= 0) {
            uint4* dst = (uint4*)(X + (size_t)c * D + h * 64);
            const uint4* srcl = (const uint4*)(a_s + r * LDSTR + h * 64);
            #pragma unroll
            for (int j = 0; j < 8; j++) dst[j] = srcl[j];   // FIX: 8 uint4 = 64 bf16 (was 4)
        }
    }
}

// ============ root: out[0] = dot((raw0 + y1 + y2)/3, score_W) ============
__global__ __launch_bounds__(128) void root_kernel(
    const unsigned short* __restrict__ X, const float* __restrict__ sW,
    float* __restrict__ out)
{
    __shared__ float red[128];
    const int t = threadIdx.x;
    const float hf = (bf2f(X[t]) + bf2f(X[128 + t]) + bf2f(X[256 + t])) * (1.0f / 3.0f);
    red[t] = hf * sW[t];
    __syncthreads();
    for (int s = 64; s > 0; s >>= 1) { if (t < s) red[t] += red[t + s]; __syncthreads(); }
    if (t == 0) out[0] = red[0];
}

extern "C" void kernel_launch(void* const* d_in, const int* in_sizes, int n_in,
                              void* d_out, int out_size, void* d_ws, size_t ws_size,
                              hipStream_t stream) {
    const int*   data      = (const int*)d_in[0];
    const int*   edges     = (const int*)d_in[1];
    const float* data_vecs = (const float*)d_in[2];
    const float* data_W    = (const float*)d_in[3];
    const float* data_b    = (const float*)d_in[4];
    const float* edge_W    = (const float*)d_in[5];
    const float* edge_b    = (const float*)d_in[6];
    const float* score_W   = (const float*)d_in[7];
    float* out = (float*)d_out;

    const int Nn = in_sizes[0];          // 2^18 - 1
    const int NI = Nn >> 1;              // internal nodes: 2^17 - 1
    const int PERM_TOTAL = (Nn - 1) + LVLPAD * NLVL;

    char* w = (char*)d_ws;
    size_t off = 0;
    unsigned short* X = (unsigned short*)(w + off); off += (size_t)Nn * D * 2;   // bf16 rows
    int* perm = (int*)(w + off);  off += (size_t)PERM_TOTAL * 4;
    off = (off + 255) & ~(size_t)255;
    int* gstart = (int*)(w + off); off += NLVL * 9 * 4;
    int* gcnt   = (int*)(w + off); off += NLVL * 8 * 4;
    int* ctr    = (int*)(w + off); off += NLVL * 8 * 4;
    off = (off + 255) & ~(size_t)255;
    float* Ccomp = (float*)(w + off); off += (size_t)8 * D * D * 4;
    float* dcomp = (float*)(w + off); off += 8 * D * 4;
    float* sv    = (float*)(w + off); off += D * 4;
    float* s0    = (float*)(w + off); off += 256;
    off = (off + 255) & ~(size_t)255;
    unsigned short* ewt = (unsigned short*)(w + off); off += (size_t)8 * D * D * 2;
    unsigned short* cwt = (unsigned short*)(w + off); off += (size_t)8 * D * D * 2;
    unsigned short* dwt = (unsigned short*)(w + off); off += (size_t)D * D * 2;

    hipMemsetAsync(perm, 0xFF, (size_t)PERM_TOTAL * 4, stream);
    hipMemsetAsync(gstart, 0, (size_t)(NLVL * 9 + NLVL * 8 + NLVL * 8) * 4, stream);

    count_kernel<<<128, 256, 0, stream>>>(edges, gcnt, Nn);
    prefix_sv_kernel<<<1, 256, 0, stream>>>(gcnt, gstart, data_W, data_b, score_W, sv, s0);
    place_kernel<<<(Nn - 1 + CHUNK - 1) / CHUNK, 256, 0, stream>>>(edges, gstart, ctr, perm, Nn);
    compose_kernel<<<32, 256, 0, stream>>>(data_W, data_b, edge_W, edge_b, Ccomp, dcomp);
    convert_kernel<<<17, 256, 0, stream>>>(edge_W, Ccomp, data_W, ewt, cwt, dwt);
    embed_kernel<<<(NI + TS - 1) / TS, 256, 0, stream>>>(data, data_vecs, dwt, data_b, X, NI);

    for (int l = NLVL - 1; l >= 0; l--) {
        const int M = 2 << l;            // children count at this level
        const int lbase = ((2 << l) - 2) + LVLPAD * l;
        const int gblocks = (M + TS - 1) / TS + 8;
        const int leaf = (l == NLVL - 1) ? 1 : 0;
        tree_gemm_kernel<<<gblocks, 256, 0, stream>>>(
            X, data_vecs, data, perm, gstart + l * 9,
            leaf ? cwt : ewt,
            leaf ? dcomp : edge_b,
            leaf ? sv : score_W,
            s0, out, lbase, leaf);
    }
    root_kernel<<<1, 128, 0, stream>>>(X, score_W, out);
}